// Round 2
// baseline (262.665 us; speedup 1.0000x reference)
//
#include <hip/hip_runtime.h>

#define B_ 16
#define C_ 256
#define N_ 16384      // 128*128
#define G_ 4          // batches per phased group (64 MiB x working set -> L3-resident)
#define NGRP_ (B_ / G_)
#define CC_ 4         // channel chunks in K1 (keeps 256 blocks/phase = full chip)
#define CCH_ (C_ / CC_)
#define NT_ 16        // n-tiles of 1024
#define NTILE_ 1024
#define R_ 16

// ---------------------------------------------------------------------------
// K1: partial colsums over channel chunks for one batch-group.
// grid (G_, NT_, CC_) x 256 thr. Block sums 64 channels over a 1024-n tile.
// part[bg][chunk][n]. This is the only pass that reads x from HBM.
// ---------------------------------------------------------------------------
__global__ void k1_partial(const float* __restrict__ x,
                           float* __restrict__ part, int g0) {
    const int bg = blockIdx.x;
    const int b = g0 + bg;
    const int tile = blockIdx.y;
    const int chunk = blockIdx.z;
    const int n0 = tile * NTILE_ + threadIdx.x * 4;
    const float* xb = x + ((size_t)b * C_ + chunk * CCH_) * N_ + n0;

    float4 acc = make_float4(0.f, 0.f, 0.f, 0.f);
#pragma unroll 8
    for (int c = 0; c < CCH_; ++c) {
        float4 vx = *reinterpret_cast<const float4*>(xb + (size_t)c * N_);
        acc.x += vx.x; acc.y += vx.y; acc.z += vx.z; acc.w += vx.w;
    }
    *reinterpret_cast<float4*>(part + ((size_t)(bg * CC_ + chunk)) * N_ + n0) = acc;
}

// ---------------------------------------------------------------------------
// K1b: reduce chunk partials -> colsum[bg][n]; per-tile batch totals Tpart.
// grid (G_, NT_) x 256 thr. ~1 MiB traffic, all L2.
// ---------------------------------------------------------------------------
__global__ void k1b_reduce(const float* __restrict__ part,
                           float* __restrict__ colsum,
                           float* __restrict__ Tpart) {
    const int bg = blockIdx.x;
    const int tile = blockIdx.y;
    const int tid = threadIdx.x;
    const int n0 = tile * NTILE_ + tid * 4;

    float4 acc = make_float4(0.f, 0.f, 0.f, 0.f);
#pragma unroll
    for (int ch = 0; ch < CC_; ++ch) {
        float4 p = *reinterpret_cast<const float4*>(
            part + ((size_t)(bg * CC_ + ch)) * N_ + n0);
        acc.x += p.x; acc.y += p.y; acc.z += p.z; acc.w += p.w;
    }
    *reinterpret_cast<float4*>(colsum + bg * N_ + n0) = acc;

    float s = acc.x + acc.y + acc.z + acc.w;
#pragma unroll
    for (int off = 32; off; off >>= 1) s += __shfl_down(s, off, 64);
    __shared__ float red[4];
    if ((tid & 63) == 0) red[tid >> 6] = s;
    __syncthreads();
    if (tid == 0) Tpart[bg * NT_ + tile] = red[0] + red[1] + red[2] + red[3];
}

// ---------------------------------------------------------------------------
// K2: v[b,c] = sum_n x[b,c,n]*(colsum[bg,n] - T/N) / ((N-1)*C)
// grid (C_, G_) x 256 thr; x row should be L3-resident from K1.
// ---------------------------------------------------------------------------
__global__ void k2_v(const float* __restrict__ x,
                     const float* __restrict__ colsum,
                     const float* __restrict__ Tpart,
                     float* __restrict__ v, int g0) {
    const int c = blockIdx.x;
    const int bg = blockIdx.y;
    const int b = g0 + bg;
    const int tid = threadIdx.x;

    float Tb = 0.f;
#pragma unroll
    for (int t = 0; t < NT_; ++t) Tb += Tpart[bg * NT_ + t];
    const float mean_s = Tb / (float)N_;

    const float* xr = x + ((size_t)b * C_ + c) * N_;
    const float* cs = colsum + bg * N_;

    float acc = 0.f;
#pragma unroll 4
    for (int n = tid * 4; n < N_; n += 256 * 4) {
        float4 vx = *reinterpret_cast<const float4*>(xr + n);
        float4 vs = *reinterpret_cast<const float4*>(cs + n);
        acc += vx.x * (vs.x - mean_s) + vx.y * (vs.y - mean_s)
             + vx.z * (vs.z - mean_s) + vx.w * (vs.w - mean_s);
    }
#pragma unroll
    for (int off = 32; off; off >>= 1) acc += __shfl_down(acc, off, 64);
    __shared__ float red[4];
    if ((tid & 63) == 0) red[tid >> 6] = acc;
    __syncthreads();
    if (tid == 0) {
        const float denom = (float)(N_ - 1) * (float)C_;
        v[b * C_ + c] = (red[0] + red[1] + red[2] + red[3]) / denom;
    }
}

// ---------------------------------------------------------------------------
// K4: fused MLP-gate + scale. grid (G_, C_) x 256 thr; block owns row (b,c).
// Each block recomputes h1 (4096 MACs spread over 256 threads) - negligible
// vs the 64 KiB row move. x row L3-resident; out write is the HBM cost.
// ---------------------------------------------------------------------------
__global__ void k4_gate_scale(const float* __restrict__ x,
                              const float* __restrict__ v,
                              const float* __restrict__ w1,
                              const float* __restrict__ b1,
                              const float* __restrict__ w2,
                              const float* __restrict__ b2,
                              float* __restrict__ out, int g0) {
    const int b = g0 + blockIdx.x;
    const int c = blockIdx.y;
    const int tid = threadIdx.x;

    __shared__ float vl[C_];
    __shared__ float hpart[R_][16];
    __shared__ float h1[R_];

    vl[tid] = v[b * C_ + tid];
    __syncthreads();

    {   // h1 partials: thread = (i, cc) over 16-channel slices
        const int i = tid >> 4;
        const int cc = tid & 15;
        float a = 0.f;
#pragma unroll
        for (int k = 0; k < 16; ++k)
            a += vl[cc * 16 + k] * w1[i * C_ + cc * 16 + k];
        hpart[i][cc] = a;
    }
    __syncthreads();
    if (tid < R_) {
        float a = b1[tid];
#pragma unroll
        for (int k = 0; k < 16; ++k) a += hpart[tid][k];
        h1[tid] = a > 0.f ? a : 0.f;
    }
    __syncthreads();

    float a = b2[c];
#pragma unroll
    for (int i = 0; i < R_; ++i) a += h1[i] * w2[c * R_ + i];
    const float g = 1.f / (1.f + __expf(-a));

    const float* xr = x + ((size_t)b * C_ + c) * N_;
    float* orow = out + ((size_t)b * C_ + c) * N_;
#pragma unroll 4
    for (int n = tid * 4; n < N_; n += 256 * 4) {
        float4 vx = *reinterpret_cast<const float4*>(xr + n);
        float4 r = make_float4(vx.x * g, vx.y * g, vx.z * g, vx.w * g);
        *reinterpret_cast<float4*>(orow + n) = r;
    }
}

extern "C" void kernel_launch(void* const* d_in, const int* in_sizes, int n_in,
                              void* d_out, int out_size, void* d_ws, size_t ws_size,
                              hipStream_t stream) {
    (void)in_sizes; (void)n_in; (void)out_size; (void)ws_size;
    const float* x  = (const float*)d_in[0];
    const float* w1 = (const float*)d_in[1];
    const float* b1 = (const float*)d_in[2];
    const float* w2 = (const float*)d_in[3];
    const float* b2 = (const float*)d_in[4];
    float* out = (float*)d_out;

    float* ws     = (float*)d_ws;
    float* part   = ws;                               // G_*CC_*N_ = 262144
    float* colsum = part + (size_t)G_ * CC_ * N_;     // G_*N_     = 65536
    float* Tpart  = colsum + (size_t)G_ * N_;         // G_*NT_    = 64
    float* v      = Tpart + G_ * NT_;                 // B_*C_     = 4096

    for (int g = 0; g < NGRP_; ++g) {
        const int g0 = g * G_;
        hipLaunchKernelGGL(k1_partial, dim3(G_, NT_, CC_), dim3(256), 0, stream,
                           x, part, g0);
        hipLaunchKernelGGL(k1b_reduce, dim3(G_, NT_), dim3(256), 0, stream,
                           part, colsum, Tpart);
        hipLaunchKernelGGL(k2_v, dim3(C_, G_), dim3(256), 0, stream,
                           x, colsum, Tpart, v, g0);
        hipLaunchKernelGGL(k4_gate_scale, dim3(G_, C_), dim3(256), 0, stream,
                           x, v, w1, b1, w2, b2, out, g0);
    }
}

// Round 3
// 182.336 us; speedup vs baseline: 1.4406x; 1.4406x over previous
//
#include <hip/hip_runtime.h>

#define B_ 16
#define C_ 256
#define N_ 16384      // 128*128
#define R_ 16
#define SUB_ 32       // n per subtile staged in LDS
#define LSTR_ 257     // C_+1 pad -> <=2-way LDS bank aliasing everywhere (free)

// ---------------------------------------------------------------------------
// kA: fused stats pass. Each block owns NSUB*32 consecutive n for one batch.
// Per 32-n subtile: stage x[b, 0:256, n0:n0+32] in LDS (transposed [n][c]),
// compute colsum[n] exactly (channel dim is block-local), then accumulate
//   P[c]  += sum_n tile[n][c] * colsum[n]
//   RS[c] += sum_n tile[n][c]
// One HBM read of x total; v is later P - (T/N)*RS (T = sum_c RS).
// LDS ~34 KiB -> 4 blocks/CU -> 16 waves/CU.
// ---------------------------------------------------------------------------
template<int NSUB>
__global__ __launch_bounds__(256, 4)
void kA(const float* __restrict__ x,
        float* __restrict__ Ppart,
        float* __restrict__ RSpart,
        int blocksPerBatch) {
    const int blk = blockIdx.x;
    const int b = blockIdx.y;
    const int t = threadIdx.x;

    __shared__ float tile[SUB_][LSTR_];   // [n][c], padded
    __shared__ float csum_part[8][32];
    __shared__ float colsum[SUB_];

    const int nbase = blk * (NSUB * SUB_);
    const int kq = t & 7;      // which float4 within the 32-n row slice
    const int crow = t >> 3;   // 0..31 base channel row

    float accP = 0.f, accRS = 0.f;

    for (int s = 0; s < NSUB; ++s) {
        const int n0 = nbase + s * SUB_;
        // ---- stage: 8 rows/thread-group, coalesced 128B segments per row
#pragma unroll
        for (int r = 0; r < 8; ++r) {
            const int c = crow + (r << 5);
            float4 v = *reinterpret_cast<const float4*>(
                x + ((size_t)b * C_ + c) * N_ + n0 + (kq << 2));
            tile[(kq << 2) + 0][c] = v.x;
            tile[(kq << 2) + 1][c] = v.y;
            tile[(kq << 2) + 2][c] = v.z;
            tile[(kq << 2) + 3][c] = v.w;
        }
        __syncthreads();
        // ---- colsum over channels: thread = (n = t&31, oct = t>>5)
        {
            const int n = t & 31, oct = t >> 5;
            float cs = 0.f;
#pragma unroll
            for (int i = 0; i < 32; ++i) cs += tile[n][(oct << 5) + i];
            csum_part[oct][n] = cs;
        }
        __syncthreads();
        if (t < SUB_) {
            float cs = 0.f;
#pragma unroll
            for (int o = 0; o < 8; ++o) cs += csum_part[o][t];
            colsum[t] = cs;
        }
        __syncthreads();
        // ---- P / rowsum accumulation: thread owns channel c = t
#pragma unroll
        for (int n = 0; n < SUB_; ++n) {
            const float tv = tile[n][t];
            accP += tv * colsum[n];
            accRS += tv;
        }
        __syncthreads();   // tile reused next subtile
    }
    Ppart [((size_t)b * blocksPerBatch + blk) * C_ + t] = accP;
    RSpart[((size_t)b * blocksPerBatch + blk) * C_ + t] = accRS;
}

// ---------------------------------------------------------------------------
// kB: reduce partials -> v -> fused MLP -> gate.  grid(B_) x 256, thread = c.
// ---------------------------------------------------------------------------
__global__ void kB(const float* __restrict__ Ppart,
                   const float* __restrict__ RSpart,
                   const float* __restrict__ w1, const float* __restrict__ b1,
                   const float* __restrict__ w2, const float* __restrict__ b2,
                   float* __restrict__ gate, int blocksPerBatch) {
    const int b = blockIdx.x;
    const int t = threadIdx.x;   // channel c

    float P = 0.f, RS = 0.f;
    for (int k = 0; k < blocksPerBatch; ++k) {
        P  += Ppart [((size_t)b * blocksPerBatch + k) * C_ + t];
        RS += RSpart[((size_t)b * blocksPerBatch + k) * C_ + t];
    }

    // T = sum_c RS  (wave shuffle + LDS across the 4 waves)
    __shared__ float red[4];
    float s = RS;
#pragma unroll
    for (int off = 32; off; off >>= 1) s += __shfl_down(s, off, 64);
    if ((t & 63) == 0) red[t >> 6] = s;
    __syncthreads();
    const float T = red[0] + red[1] + red[2] + red[3];
    const float M = T / (float)N_;
    const float denom = (float)(N_ - 1) * (float)C_;

    __shared__ float vl[C_];
    vl[t] = (P - M * RS) / denom;
    __syncthreads();

    // MLP: h1 = relu(v @ w1^T + b1); gate = sigmoid(h1 @ w2^T + b2)
    __shared__ float hpart[R_][16];
    __shared__ float h1[R_];
    {
        const int i = t >> 4, cc = t & 15;
        float a = 0.f;
#pragma unroll
        for (int k = 0; k < 16; ++k)
            a += vl[(cc << 4) + k] * w1[i * C_ + (cc << 4) + k];
        hpart[i][cc] = a;
    }
    __syncthreads();
    if (t < R_) {
        float a = b1[t];
#pragma unroll
        for (int k = 0; k < 16; ++k) a += hpart[t][k];
        h1[t] = a > 0.f ? a : 0.f;
    }
    __syncthreads();

    float a = b2[t];
#pragma unroll
    for (int i = 0; i < R_; ++i) a += h1[i] * w2[t * R_ + i];
    gate[b * C_ + t] = 1.f / (1.f + __expf(-a));
}

// ---------------------------------------------------------------------------
// kC: out = x * gate[b,c], grid-stride float4 (R0-proven).
// ---------------------------------------------------------------------------
__global__ void kC(const float* __restrict__ x,
                   const float* __restrict__ gate,
                   float* __restrict__ out) {
    const size_t total4 = (size_t)B_ * C_ * N_ / 4;
    for (size_t i = (size_t)blockIdx.x * blockDim.x + threadIdx.x; i < total4;
         i += (size_t)gridDim.x * blockDim.x) {
        const int bc = (int)(i >> 12);           // N_/4 = 4096 float4 per (b,c)
        const float g = gate[bc];
        float4 vx = reinterpret_cast<const float4*>(x)[i];
        float4 r = make_float4(vx.x * g, vx.y * g, vx.z * g, vx.w * g);
        reinterpret_cast<float4*>(out)[i] = r;
    }
}

extern "C" void kernel_launch(void* const* d_in, const int* in_sizes, int n_in,
                              void* d_out, int out_size, void* d_ws, size_t ws_size,
                              hipStream_t stream) {
    (void)in_sizes; (void)n_in; (void)out_size;
    const float* x  = (const float*)d_in[0];
    const float* w1 = (const float*)d_in[1];
    const float* b1 = (const float*)d_in[2];
    const float* w2 = (const float*)d_in[3];
    const float* b2 = (const float*)d_in[4];
    float* out = (float*)d_out;

    // Pick partial-array granularity by available scratch (deterministic).
    const size_t need64 = (size_t)(2 * B_ * 64 * C_ + B_ * C_) * sizeof(float);
    const int bpb = (ws_size >= need64) ? 64 : 32;   // blocks per batch

    float* ws     = (float*)d_ws;
    float* Ppart  = ws;                                    // B_*bpb*C_
    float* RSpart = Ppart + (size_t)B_ * bpb * C_;         // B_*bpb*C_
    float* gate   = RSpart + (size_t)B_ * bpb * C_;        // B_*C_

    if (bpb == 64) {
        hipLaunchKernelGGL((kA<8>), dim3(64, B_), dim3(256), 0, stream,
                           x, Ppart, RSpart, 64);
    } else {
        hipLaunchKernelGGL((kA<16>), dim3(32, B_), dim3(256), 0, stream,
                           x, Ppart, RSpart, 32);
    }
    hipLaunchKernelGGL(kB, dim3(B_), dim3(256), 0, stream,
                       Ppart, RSpart, w1, b1, w2, b2, gate, bpb);
    hipLaunchKernelGGL(kC, dim3(2048), dim3(256), 0, stream,
                       x, gate, out);
}

// Round 5
// 156.630 us; speedup vs baseline: 1.6770x; 1.1641x over previous
//
#include <hip/hip_runtime.h>

#define B_ 16
#define C_ 256
#define N_ 16384      // 128*128
#define R_ 16
#define SUB_ 32       // n per subtile staged in LDS
#define LSTR_ 257     // C_+1 pad -> <=2-way LDS bank aliasing everywhere (free)

typedef float f32x4 __attribute__((ext_vector_type(4)));

// ---------------------------------------------------------------------------
// kA: fused stats pass (one HBM read of x; also warms L3 with all of x).
// Per 32-n subtile: stage x[b, 0:256, n0:n0+32] in LDS (transposed [n][c]),
// compute colsum[n], accumulate P[c] += x*colsum, RS[c] += x.
// v = (P - (T/N)*RS) / ((N-1)*C) later.  LDS ~34 KiB -> 4 blocks/CU.
// ---------------------------------------------------------------------------
template<int NSUB>
__global__ __launch_bounds__(256, 4)
void kA(const float* __restrict__ x,
        float* __restrict__ Ppart,
        float* __restrict__ RSpart,
        int blocksPerBatch) {
    const int blk = blockIdx.x;
    const int b = blockIdx.y;
    const int t = threadIdx.x;

    __shared__ float tile[SUB_][LSTR_];   // [n][c], padded
    __shared__ float csum_part[8][32];
    __shared__ float colsum[SUB_];

    const int nbase = blk * (NSUB * SUB_);
    const int kq = t & 7;      // which float4 within the 32-n row slice
    const int crow = t >> 3;   // 0..31 base channel row

    float accP = 0.f, accRS = 0.f;

    for (int s = 0; s < NSUB; ++s) {
        const int n0 = nbase + s * SUB_;
#pragma unroll
        for (int r = 0; r < 8; ++r) {
            const int c = crow + (r << 5);
            float4 v = *reinterpret_cast<const float4*>(
                x + ((size_t)b * C_ + c) * N_ + n0 + (kq << 2));
            tile[(kq << 2) + 0][c] = v.x;
            tile[(kq << 2) + 1][c] = v.y;
            tile[(kq << 2) + 2][c] = v.z;
            tile[(kq << 2) + 3][c] = v.w;
        }
        __syncthreads();
        {
            const int n = t & 31, oct = t >> 5;
            float cs = 0.f;
#pragma unroll
            for (int i = 0; i < 32; ++i) cs += tile[n][(oct << 5) + i];
            csum_part[oct][n] = cs;
        }
        __syncthreads();
        if (t < SUB_) {
            float cs = 0.f;
#pragma unroll
            for (int o = 0; o < 8; ++o) cs += csum_part[o][t];
            colsum[t] = cs;
        }
        __syncthreads();
#pragma unroll
        for (int n = 0; n < SUB_; ++n) {
            const float tv = tile[n][t];
            accP += tv * colsum[n];
            accRS += tv;
        }
        __syncthreads();
    }
    Ppart [((size_t)b * blocksPerBatch + blk) * C_ + t] = accP;
    RSpart[((size_t)b * blocksPerBatch + blk) * C_ + t] = accRS;
}

// ---------------------------------------------------------------------------
// kB: reduce partials -> v -> fused MLP -> gate.  grid(B_) x 256, thread = c.
// ---------------------------------------------------------------------------
__global__ void kB(const float* __restrict__ Ppart,
                   const float* __restrict__ RSpart,
                   const float* __restrict__ w1, const float* __restrict__ b1,
                   const float* __restrict__ w2, const float* __restrict__ b2,
                   float* __restrict__ gate, int blocksPerBatch) {
    const int b = blockIdx.x;
    const int t = threadIdx.x;   // channel c

    float P = 0.f, RS = 0.f;
    for (int k = 0; k < blocksPerBatch; ++k) {
        P  += Ppart [((size_t)b * blocksPerBatch + k) * C_ + t];
        RS += RSpart[((size_t)b * blocksPerBatch + k) * C_ + t];
    }

    __shared__ float red[4];
    float s = RS;
#pragma unroll
    for (int off = 32; off; off >>= 1) s += __shfl_down(s, off, 64);
    if ((t & 63) == 0) red[t >> 6] = s;
    __syncthreads();
    const float T = red[0] + red[1] + red[2] + red[3];
    const float M = T / (float)N_;
    const float denom = (float)(N_ - 1) * (float)C_;

    __shared__ float vl[C_];
    vl[t] = (P - M * RS) / denom;
    __syncthreads();

    __shared__ float hpart[R_][16];
    __shared__ float h1[R_];
    {
        const int i = t >> 4, cc = t & 15;
        float a = 0.f;
#pragma unroll
        for (int k = 0; k < 16; ++k)
            a += vl[(cc << 4) + k] * w1[i * C_ + (cc << 4) + k];
        hpart[i][cc] = a;
    }
    __syncthreads();
    if (t < R_) {
        float a = b1[t];
#pragma unroll
        for (int k = 0; k < 16; ++k) a += hpart[t][k];
        h1[t] = a > 0.f ? a : 0.f;
    }
    __syncthreads();

    float a = b2[t];
#pragma unroll
    for (int i = 0; i < R_; ++i) a += h1[i] * w2[t * R_ + i];
    gate[b * C_ + t] = 1.f / (1.f + __expf(-a));
}

// ---------------------------------------------------------------------------
// kC: out = x * gate[b,c].  x read normally (L3 hits from kA's warm);
// out written NON-TEMPORALLY (nt -> LLC no-allocate) so x stays resident.
// ---------------------------------------------------------------------------
__global__ void kC(const float* __restrict__ x,
                   const float* __restrict__ gate,
                   float* __restrict__ out) {
    const size_t total4 = (size_t)B_ * C_ * N_ / 4;
    for (size_t i = (size_t)blockIdx.x * blockDim.x + threadIdx.x; i < total4;
         i += (size_t)gridDim.x * blockDim.x) {
        const int bc = (int)(i >> 12);           // N_/4 = 4096 float4 per (b,c)
        const float g = gate[bc];
        float4 vx = reinterpret_cast<const float4*>(x)[i];
        f32x4 r;
        r.x = vx.x * g; r.y = vx.y * g; r.z = vx.z * g; r.w = vx.w * g;
        __builtin_nontemporal_store(r, reinterpret_cast<f32x4*>(out) + i);
    }
}

extern "C" void kernel_launch(void* const* d_in, const int* in_sizes, int n_in,
                              void* d_out, int out_size, void* d_ws, size_t ws_size,
                              hipStream_t stream) {
    (void)in_sizes; (void)n_in; (void)out_size;
    const float* x  = (const float*)d_in[0];
    const float* w1 = (const float*)d_in[1];
    const float* b1 = (const float*)d_in[2];
    const float* w2 = (const float*)d_in[3];
    const float* b2 = (const float*)d_in[4];
    float* out = (float*)d_out;

    const size_t need64 = (size_t)(2 * B_ * 64 * C_ + B_ * C_) * sizeof(float);
    const int bpb = (ws_size >= need64) ? 64 : 32;   // blocks per batch

    float* ws     = (float*)d_ws;
    float* Ppart  = ws;                                    // B_*bpb*C_
    float* RSpart = Ppart + (size_t)B_ * bpb * C_;         // B_*bpb*C_
    float* gate   = RSpart + (size_t)B_ * bpb * C_;        // B_*C_

    if (bpb == 64) {
        hipLaunchKernelGGL((kA<8>), dim3(64, B_), dim3(256), 0, stream,
                           x, Ppart, RSpart, 64);
    } else {
        hipLaunchKernelGGL((kA<16>), dim3(32, B_), dim3(256), 0, stream,
                           x, Ppart, RSpart, 32);
    }
    hipLaunchKernelGGL(kB, dim3(B_), dim3(256), 0, stream,
                       Ppart, RSpart, w1, b1, w2, b2, gate, bpb);
    hipLaunchKernelGGL(kC, dim3(2048), dim3(256), 0, stream,
                       x, gate, out);
}